// Round 3
// baseline (147.251 us; speedup 1.0000x reference)
//
#include <hip/hip_runtime.h>

#define NB 4
#define CH 256
#define CL 512
#define HH 64
#define HWD 64
#define LHD 32
#define LWD 32
#define PLANE (HH*HWD)      // 4096
#define LPLANE (LHD*LWD)    // 1024
#define NPIX (NB*PLANE)     // 16384

// ---------------- Kernel 1a: BN partial sums (block = (c, b)) ----------------
__global__ void bn_stage1_kernel(const float* __restrict__ high,
                                 float* __restrict__ partS,
                                 float* __restrict__ partS2) {
    int bid = blockIdx.x;            // c*4 + b, 1024 blocks
    int b = bid & 3;
    int c = bid >> 2;
    int tid = threadIdx.x;           // 256
    const float* p = high + ((size_t)(b * CH + c)) * PLANE;
    float s = 0.f, s2 = 0.f;
    #pragma unroll
    for (int i = 0; i < 4; ++i) {
        float4 v = *(const float4*)(p + (i * 256 + tid) * 4);
        s  += v.x + v.y + v.z + v.w;
        s2 += v.x * v.x + v.y * v.y + v.z * v.z + v.w * v.w;
    }
    __shared__ float sm1[4], sm2[4];
    int lane = tid & 63, wid = tid >> 6;
    #pragma unroll
    for (int off = 32; off > 0; off >>= 1) {
        s  += __shfl_down(s, off);
        s2 += __shfl_down(s2, off);
    }
    if (lane == 0) { sm1[wid] = s; sm2[wid] = s2; }
    __syncthreads();
    if (tid == 0) {
        partS[bid]  = sm1[0] + sm1[1] + sm1[2] + sm1[3];
        partS2[bid] = sm2[0] + sm2[1] + sm2[2] + sm2[3];
    }
}

// ---------------- Kernel 1b: finalize scale/shift ----------------
__global__ void bn_stage2_kernel(const float* __restrict__ partS,
                                 const float* __restrict__ partS2,
                                 const float* __restrict__ gamma,
                                 const float* __restrict__ beta,
                                 float* __restrict__ scale,
                                 float* __restrict__ shift) {
    int c = threadIdx.x;             // 256
    float S  = partS[c*4+0] + partS[c*4+1] + partS[c*4+2] + partS[c*4+3];
    float S2 = partS2[c*4+0] + partS2[c*4+1] + partS2[c*4+2] + partS2[c*4+3];
    const float invN = 1.f / (float)(NB * PLANE);
    float mean = S * invN;
    float var  = S2 * invN - mean * mean;
    float sc = gamma[c] * rsqrtf(var + 1e-5f);
    scale[c] = sc;
    shift[c] = beta[c] - mean * sc;
}

// ------- Kernel 2: channels-last transpose + affine + pooled down -------
__global__ void transpose_kernel(const float* __restrict__ high,
                                 const float* __restrict__ scale,
                                 const float* __restrict__ shift,
                                 float* __restrict__ Ht,
                                 float* __restrict__ Dt) {
    int bid = blockIdx.x;            // 4*32*4 = 512
    int cchunk = bid & 3;
    int r = (bid >> 2) & 31;
    int b = bid >> 7;
    int c0 = cchunk * 64;
    __shared__ float tile[2][64][65];
    int tid = threadIdx.x;           // 256

    int xg = tid & 15;
    int jr = tid >> 4;
    #pragma unroll
    for (int i = 0; i < 8; ++i) {
        int j = i * 16 + jr;         // 0..127
        int cl = j >> 1, row = j & 1;
        const float* p = high + (((size_t)(b * CH + c0 + cl) * HH + (2 * r + row)) * HWD) + xg * 4;
        float4 v = *(const float4*)p;
        tile[row][cl][xg * 4 + 0] = v.x;
        tile[row][cl][xg * 4 + 1] = v.y;
        tile[row][cl][xg * 4 + 2] = v.z;
        tile[row][cl][xg * 4 + 3] = v.w;
    }
    __syncthreads();

    int c = tid & 63;
    float sc = scale[c0 + c], sh = shift[c0 + c];

    int pg = tid >> 6;               // 0..3
    #pragma unroll
    for (int i = 0; i < 32; ++i) {
        int pix = i * 4 + pg;        // 0..127
        int row = pix >> 6, x = pix & 63;
        float v = tile[row][c][x] * sc + sh;
        Ht[(((size_t)(b * HH + 2 * r + row) * HWD) + x) * CH + c0 + c] = v;
    }

    #pragma unroll
    for (int i = 0; i < 8; ++i) {
        int lx = i * 4 + pg;         // 0..31
        float sum = tile[0][c][2*lx] + tile[0][c][2*lx+1]
                  + tile[1][c][2*lx] + tile[1][c][2*lx+1];
        Dt[(((size_t)(b * LHD + r) * LWD) + lx) * CH + c0 + c] = 0.25f * sum * sc + sh;
    }
}

// ------- Kernel 3: wave per 2x2 pixel block, 16 lanes x 16 ch -------
__global__ void scores_softmax_kernel(const float* __restrict__ Ht,
                                      const float* __restrict__ Dt,
                                      const float* __restrict__ bias,
                                      float* __restrict__ att) {
    int tid = threadIdx.x;
    int lane = tid & 63, wid = tid >> 6;
    int t = blockIdx.x * 4 + wid;        // [0, 4096): 2x2 block index
    int b  = t >> 10;
    int by = (t >> 5) & 31;
    int bx = t & 31;
    int g  = lane >> 4;                  // pixel in 2x2 block
    int y  = by * 2 + (g >> 1);
    int x  = bx * 2 + (g & 1);
    int c0 = (lane & 15) * 16;

    const float* Hb = Ht + (size_t)b * PLANE * CH + c0;
    const float* Db = Dt + (size_t)b * LPLANE * CH + c0;

    float acc[9];
    #pragma unroll
    for (int k = 0; k < 9; ++k) {
        int dy = k / 3, dx = k % 3;
        int uy = y + dy - 1, ux = x + dx - 1;
        float4 h0 = make_float4(0.f,0.f,0.f,0.f), h1 = h0, h2 = h0, h3 = h0;
        if (uy >= 0 && uy < HH && ux >= 0 && ux < HWD) {
            const float* hp = Hb + ((size_t)((uy << 6) + ux)) * CH;
            h0 = *(const float4*)(hp + 0);
            h1 = *(const float4*)(hp + 4);
            h2 = *(const float4*)(hp + 8);
            h3 = *(const float4*)(hp + 12);
        }
        int vy = by + dy - 1, vx = bx + dx - 1;
        float4 d0 = make_float4(0.f,0.f,0.f,0.f), d1 = d0, d2 = d0, d3 = d0;
        if (vy >= 0 && vy < LHD && vx >= 0 && vx < LWD) {
            const float* dp = Db + ((size_t)((vy << 5) + vx)) * CH;
            d0 = *(const float4*)(dp + 0);
            d1 = *(const float4*)(dp + 4);
            d2 = *(const float4*)(dp + 8);
            d3 = *(const float4*)(dp + 12);
        }
        float a = 0.f;
        float t0;
        t0 = h0.x - d0.x; a += t0 * t0;  t0 = h0.y - d0.y; a += t0 * t0;
        t0 = h0.z - d0.z; a += t0 * t0;  t0 = h0.w - d0.w; a += t0 * t0;
        t0 = h1.x - d1.x; a += t0 * t0;  t0 = h1.y - d1.y; a += t0 * t0;
        t0 = h1.z - d1.z; a += t0 * t0;  t0 = h1.w - d1.w; a += t0 * t0;
        t0 = h2.x - d2.x; a += t0 * t0;  t0 = h2.y - d2.y; a += t0 * t0;
        t0 = h2.z - d2.z; a += t0 * t0;  t0 = h2.w - d2.w; a += t0 * t0;
        t0 = h3.x - d3.x; a += t0 * t0;  t0 = h3.y - d3.y; a += t0 * t0;
        t0 = h3.z - d3.z; a += t0 * t0;  t0 = h3.w - d3.w; a += t0 * t0;
        acc[k] = a;
    }

    // reduce over the 16 lanes of each group
    #pragma unroll
    for (int off = 1; off < 16; off <<= 1) {
        #pragma unroll
        for (int k = 0; k < 9; ++k) acc[k] += __shfl_xor(acc[k], off);
    }

    // softmax over k, computed redundantly on all lanes (no divergence)
    float e[9];
    float m = -1e30f;
    #pragma unroll
    for (int k = 0; k < 9; ++k) { e[k] = acc[k] + bias[k]; m = fmaxf(m, e[k]); }
    float sum = 0.f;
    #pragma unroll
    for (int k = 0; k < 9; ++k) { e[k] = __expf(e[k] - m); sum += e[k]; }
    float inv = 1.f / sum;

    int kk = lane & 15;
    float v = 0.f;
    #pragma unroll
    for (int k = 0; k < 9; ++k) v = (kk == k) ? e[k] * inv : v;
    if (kk < 9)
        att[(size_t)b * 9 * PLANE + kk * PLANE + (y << 6) + x] = v;
}

// ------- Kernel 4: out; thread = (b, 4 l, y, 4 low-x) -> 8 out-x -------
__global__ void out_kernel(const float* __restrict__ low,
                           const float* __restrict__ att,
                           float* __restrict__ out) {
    int idx = blockIdx.x * 256 + threadIdx.x;   // 262144
    int xg = idx & 7;            // 8 groups of 4 low-x
    int y  = (idx >> 3) & 63;
    int l4 = (idx >> 9) & 127;
    int b  = idx >> 16;
    int lx0 = xg * 4;
    int x0  = lx0 * 2;           // out x0..x0+7
    int l0  = l4 * 4;
    int ly  = y >> 1;

    const float* ap = att + (size_t)b * 9 * PLANE + (y << 6) + x0;
    float a[9][8];
    #pragma unroll
    for (int k = 0; k < 9; ++k) {
        float4 v0 = *(const float4*)(ap + k * PLANE);
        float4 v1 = *(const float4*)(ap + k * PLANE + 4);
        a[k][0] = v0.x; a[k][1] = v0.y; a[k][2] = v0.z; a[k][3] = v0.w;
        a[k][4] = v1.x; a[k][5] = v1.y; a[k][6] = v1.z; a[k][7] = v1.w;
    }

    #pragma unroll
    for (int li = 0; li < 4; ++li) {
        const float* lp = low + (size_t)(b * CL + l0 + li) * LPLANE;
        float lv[3][6];          // low x window [lx0-1, lx0+4]
        #pragma unroll
        for (int dy = 0; dy < 3; ++dy) {
            int lyy = ly + dy - 1;
            if (lyy >= 0 && lyy < LHD) {
                const float* rp = lp + lyy * LWD;
                float4 mid = *(const float4*)(rp + lx0);
                lv[dy][1] = mid.x; lv[dy][2] = mid.y; lv[dy][3] = mid.z; lv[dy][4] = mid.w;
                lv[dy][0] = (lx0 > 0) ? rp[lx0 - 1] : 0.f;
                lv[dy][5] = (lx0 + 4 < LWD) ? rp[lx0 + 4] : 0.f;
            } else {
                #pragma unroll
                for (int j = 0; j < 6; ++j) lv[dy][j] = 0.f;
            }
        }
        float o[8];
        #pragma unroll
        for (int xi = 0; xi < 8; ++xi) {
            int base = xi >> 1;   // local low-x index offset
            float s = 0.f;
            #pragma unroll
            for (int k = 0; k < 9; ++k) {
                int dy = k / 3, dx = k % 3;
                s += a[k][xi] * lv[dy][base + dx];
            }
            o[xi] = s;
        }
        float* op = out + (size_t)(b * CL + l0 + li) * PLANE + (y << 6) + x0;
        *(float4*)(op)     = make_float4(o[0], o[1], o[2], o[3]);
        *(float4*)(op + 4) = make_float4(o[4], o[5], o[6], o[7]);
    }
}

extern "C" void kernel_launch(void* const* d_in, const int* in_sizes, int n_in,
                              void* d_out, int out_size, void* d_ws, size_t ws_size,
                              hipStream_t stream) {
    const float* low   = (const float*)d_in[0];
    const float* high  = (const float*)d_in[1];
    const float* gamma = (const float*)d_in[2];
    const float* beta  = (const float*)d_in[3];
    const float* bias  = (const float*)d_in[4];
    float* out = (float*)d_out;

    float* ws = (float*)d_ws;
    float* partS  = ws;                       // 1024
    float* partS2 = partS + 1024;             // 1024
    float* scale  = partS2 + 1024;            // 256
    float* shift  = scale + 256;              // 256
    float* Ht     = shift + 256;              // 4*64*64*256
    float* Dt     = Ht + (size_t)NB * PLANE * CH;    // 4*32*32*256
    float* att    = Dt + (size_t)NB * LPLANE * CH;   // 4*9*4096

    bn_stage1_kernel<<<1024, 256, 0, stream>>>(high, partS, partS2);
    bn_stage2_kernel<<<1, 256, 0, stream>>>(partS, partS2, gamma, beta, scale, shift);
    transpose_kernel<<<512, 256, 0, stream>>>(high, scale, shift, Ht, Dt);
    scores_softmax_kernel<<<1024, 256, 0, stream>>>(Ht, Dt, bias, att);
    out_kernel<<<1024, 256, 0, stream>>>(low, att, out);
}

// Round 4
// 53.543 us; speedup vs baseline: 2.7502x; 2.7502x over previous
//
#include <hip/hip_runtime.h>

#define NB 4
#define CH 256
#define CL 512
#define HH 64
#define HWD 64
#define LHD 32
#define LWD 32
#define PLANE (HH*HWD)      // 4096
#define LPLANE (LHD*LWD)    // 1024
#define NPIX (NB*PLANE)     // 16384

// ------- Kernel 1: channels-last transpose (raw) + raw pooled down + BN partial sums -------
// Block: (b, row-pair r, 64-channel chunk). 512 blocks x 256 threads.
__global__ void transpose_stats_kernel(const float* __restrict__ high,
                                       float* __restrict__ Ht,
                                       float* __restrict__ Dt,
                                       float* __restrict__ pS,
                                       float* __restrict__ pS2) {
    int bid = blockIdx.x;            // 4*32*4 = 512
    int cchunk = bid & 3;
    int r = (bid >> 2) & 31;
    int b = bid >> 7;
    int c0 = cchunk * 64;
    __shared__ float tile[2][64][65];
    __shared__ float sms[64][4], sms2[64][4];
    int tid = threadIdx.x;           // 256

    // load 2 rows x 64 c x 64 x
    int xg = tid & 15;
    int jr = tid >> 4;
    #pragma unroll
    for (int i = 0; i < 8; ++i) {
        int j = i * 16 + jr;         // 0..127
        int cl = j >> 1, row = j & 1;
        const float* p = high + (((size_t)(b * CH + c0 + cl) * HH + (2 * r + row)) * HWD) + xg * 4;
        float4 v = *(const float4*)p;
        tile[row][cl][xg * 4 + 0] = v.x;
        tile[row][cl][xg * 4 + 1] = v.y;
        tile[row][cl][xg * 4 + 2] = v.z;
        tile[row][cl][xg * 4 + 3] = v.w;
    }
    __syncthreads();

    int c = tid & 63;
    int pg = tid >> 6;               // 0..3

    // Ht store (raw) + per-channel partial sums
    float s = 0.f, s2 = 0.f;
    #pragma unroll
    for (int i = 0; i < 32; ++i) {
        int pix = i * 4 + pg;        // 0..127
        int row = pix >> 6, x = pix & 63;
        float v = tile[row][c][x];
        Ht[(((size_t)(b * HH + 2 * r + row) * HWD) + x) * CH + c0 + c] = v;
        s += v; s2 += v * v;
    }
    sms[c][pg] = s; sms2[c][pg] = s2;

    // Dt store (raw pooled)
    #pragma unroll
    for (int i = 0; i < 8; ++i) {
        int lx = i * 4 + pg;         // 0..31
        float sum = tile[0][c][2*lx] + tile[0][c][2*lx+1]
                  + tile[1][c][2*lx] + tile[1][c][2*lx+1];
        Dt[(((size_t)(b * LHD + r) * LWD) + lx) * CH + c0 + c] = 0.25f * sum;
    }
    __syncthreads();
    if (tid < 64) {
        float S  = sms[tid][0] + sms[tid][1] + sms[tid][2] + sms[tid][3];
        float S2 = sms2[tid][0] + sms2[tid][1] + sms2[tid][2] + sms2[tid][3];
        int cg = c0 + tid;
        pS [cg * 128 + b * 32 + r] = S;
        pS2[cg * 128 + b * 32 + r] = S2;
    }
}

// ------- Kernel 2: finalize BN -> scale/shift. 256 blocks x 128 threads. -------
__global__ void bn_finalize_kernel(const float* __restrict__ pS,
                                   const float* __restrict__ pS2,
                                   const float* __restrict__ gamma,
                                   const float* __restrict__ beta,
                                   float* __restrict__ scale,
                                   float* __restrict__ shift) {
    int c = blockIdx.x;
    int t = threadIdx.x;             // 128
    float s  = pS [c * 128 + t];
    float s2 = pS2[c * 128 + t];
    int lane = t & 63, wid = t >> 6;
    #pragma unroll
    for (int off = 32; off > 0; off >>= 1) {
        s  += __shfl_down(s, off);
        s2 += __shfl_down(s2, off);
    }
    __shared__ float a1[2], a2[2];
    if (lane == 0) { a1[wid] = s; a2[wid] = s2; }
    __syncthreads();
    if (t == 0) {
        float S  = a1[0] + a1[1];
        float S2 = a2[0] + a2[1];
        const float invN = 1.f / (float)(NB * PLANE);
        float mean = S * invN;
        float var  = S2 * invN - mean * mean;
        float sc = gamma[c] * rsqrtf(var + 1e-5f);
        scale[c] = sc;
        shift[c] = beta[c] - mean * sc;
    }
}

// ------- Kernel 3: wave-per-pixel scores + softmax -> att (r2 structure + on-the-fly affine) -------
__global__ void scores_softmax_kernel(const float* __restrict__ Ht,
                                      const float* __restrict__ Dt,
                                      const float* __restrict__ scale,
                                      const float* __restrict__ shift,
                                      const float* __restrict__ bias,
                                      float* __restrict__ att) {
    int tid = threadIdx.x;
    int lane = tid & 63, wid = tid >> 6;
    int pix = blockIdx.x * 4 + wid;      // [0, NPIX)
    int b = pix >> 12;
    int yx = pix & (PLANE - 1);
    int y = yx >> 6, x = yx & 63;
    const float* Hb = Ht + (size_t)b * PLANE * CH;
    const float* Db = Dt + (size_t)b * LPLANE * CH;
    int c4 = lane * 4;
    float4 scv = *(const float4*)(scale + c4);
    float4 shv = *(const float4*)(shift + c4);

    float acc[9];
    #pragma unroll
    for (int k = 0; k < 9; ++k) {
        int dy = k / 3, dx = k % 3;
        int yy = y + dy - 1, xx = x + dx - 1;
        float4 hv = make_float4(0.f, 0.f, 0.f, 0.f);
        if (yy >= 0 && yy < HH && xx >= 0 && xx < HWD) {
            float4 raw = *(const float4*)(Hb + ((size_t)((yy << 6) + xx)) * CH + c4);
            hv.x = fmaf(raw.x, scv.x, shv.x);
            hv.y = fmaf(raw.y, scv.y, shv.y);
            hv.z = fmaf(raw.z, scv.z, shv.z);
            hv.w = fmaf(raw.w, scv.w, shv.w);
        }
        int qy = (y >> 1) + dy - 1, qx = (x >> 1) + dx - 1;
        float4 dv = make_float4(0.f, 0.f, 0.f, 0.f);
        if (qy >= 0 && qy < LHD && qx >= 0 && qx < LWD) {
            float4 raw = *(const float4*)(Db + ((size_t)((qy << 5) + qx)) * CH + c4);
            dv.x = fmaf(raw.x, scv.x, shv.x);
            dv.y = fmaf(raw.y, scv.y, shv.y);
            dv.z = fmaf(raw.z, scv.z, shv.z);
            dv.w = fmaf(raw.w, scv.w, shv.w);
        }
        float dx0 = hv.x - dv.x, dx1 = hv.y - dv.y, dx2 = hv.z - dv.z, dx3 = hv.w - dv.w;
        acc[k] = dx0 * dx0 + dx1 * dx1 + dx2 * dx2 + dx3 * dx3;
    }
    // 64-lane butterfly reduce, all 9 accumulators
    #pragma unroll
    for (int off = 32; off > 0; off >>= 1) {
        #pragma unroll
        for (int k = 0; k < 9; ++k) acc[k] += __shfl_xor(acc[k], off);
    }
    if (lane == 0) {
        float e[9];
        float m = -1e30f;
        #pragma unroll
        for (int k = 0; k < 9; ++k) { e[k] = acc[k] + bias[k]; m = fmaxf(m, e[k]); }
        float sum = 0.f;
        #pragma unroll
        for (int k = 0; k < 9; ++k) { e[k] = __expf(e[k] - m); sum += e[k]; }
        float inv = 1.f / sum;
        float* ap = att + (size_t)b * 9 * PLANE + yx;
        #pragma unroll
        for (int k = 0; k < 9; ++k) ap[k * PLANE] = e[k] * inv;
    }
}

// ------- Kernel 4: out; block = (b, y, l-chunk), att row shared via L1 broadcast -------
__global__ void out_kernel(const float* __restrict__ low,
                           const float* __restrict__ att,
                           float* __restrict__ out) {
    int bid = blockIdx.x;        // 1024: ((b*64)+y)*4 + lc
    int lc = bid & 3;
    int y  = (bid >> 2) & 63;
    int b  = bid >> 8;
    int tid = threadIdx.x;       // 256
    int xg = tid & 7;            // 8 x-groups
    int l4 = tid >> 3;           // 32 l-groups
    int lx0 = xg * 4;
    int x0  = xg * 8;            // out x0..x0+7
    int l0  = (lc * 32 + l4) * 4;
    int ly  = y >> 1;

    const float* ap = att + (size_t)b * 9 * PLANE + (y << 6) + x0;
    float a[9][8];
    #pragma unroll
    for (int k = 0; k < 9; ++k) {
        float4 v0 = *(const float4*)(ap + k * PLANE);
        float4 v1 = *(const float4*)(ap + k * PLANE + 4);
        a[k][0] = v0.x; a[k][1] = v0.y; a[k][2] = v0.z; a[k][3] = v0.w;
        a[k][4] = v1.x; a[k][5] = v1.y; a[k][6] = v1.z; a[k][7] = v1.w;
    }

    #pragma unroll
    for (int li = 0; li < 4; ++li) {
        const float* lp = low + (size_t)(b * CL + l0 + li) * LPLANE;
        float lv[3][6];          // low x window [lx0-1, lx0+4]
        #pragma unroll
        for (int dy = 0; dy < 3; ++dy) {
            int lyy = ly + dy - 1;
            if (lyy >= 0 && lyy < LHD) {
                const float* rp = lp + lyy * LWD;
                float4 mid = *(const float4*)(rp + lx0);
                lv[dy][1] = mid.x; lv[dy][2] = mid.y; lv[dy][3] = mid.z; lv[dy][4] = mid.w;
                lv[dy][0] = (lx0 > 0) ? rp[lx0 - 1] : 0.f;
                lv[dy][5] = (lx0 + 4 < LWD) ? rp[lx0 + 4] : 0.f;
            } else {
                #pragma unroll
                for (int j = 0; j < 6; ++j) lv[dy][j] = 0.f;
            }
        }
        float o[8];
        #pragma unroll
        for (int xi = 0; xi < 8; ++xi) {
            int base = xi >> 1;
            float s = 0.f;
            #pragma unroll
            for (int k = 0; k < 9; ++k) {
                int dy = k / 3, dx = k % 3;
                s += a[k][xi] * lv[dy][base + dx];
            }
            o[xi] = s;
        }
        float* op = out + (size_t)(b * CL + l0 + li) * PLANE + (y << 6) + x0;
        *(float4*)(op)     = make_float4(o[0], o[1], o[2], o[3]);
        *(float4*)(op + 4) = make_float4(o[4], o[5], o[6], o[7]);
    }
}

extern "C" void kernel_launch(void* const* d_in, const int* in_sizes, int n_in,
                              void* d_out, int out_size, void* d_ws, size_t ws_size,
                              hipStream_t stream) {
    const float* low   = (const float*)d_in[0];
    const float* high  = (const float*)d_in[1];
    const float* gamma = (const float*)d_in[2];
    const float* beta  = (const float*)d_in[3];
    const float* bias  = (const float*)d_in[4];
    float* out = (float*)d_out;

    float* ws = (float*)d_ws;
    float* pS    = ws;                        // 256*128 = 32768
    float* pS2   = pS + 32768;                // 32768
    float* scale = pS2 + 32768;               // 256
    float* shift = scale + 256;               // 256
    float* Ht    = shift + 256;               // 4*64*64*256 = 4194304
    float* Dt    = Ht + (size_t)NB * PLANE * CH;    // 1048576
    float* att   = Dt + (size_t)NB * LPLANE * CH;   // 147456

    transpose_stats_kernel<<<512, 256, 0, stream>>>(high, Ht, Dt, pS, pS2);
    bn_finalize_kernel<<<256, 128, 0, stream>>>(pS, pS2, gamma, beta, scale, shift);
    scores_softmax_kernel<<<NPIX / 4, 256, 0, stream>>>(Ht, Dt, scale, shift, bias, att);
    out_kernel<<<1024, 256, 0, stream>>>(low, att, out);
}

// Round 5
// 39.802 us; speedup vs baseline: 3.6996x; 1.3452x over previous
//
#include <hip/hip_runtime.h>

#define NB 4
#define CH 256
#define CL 512
#define HH 64
#define HWD 64
#define LHD 32
#define LWD 32
#define PLANE (HH*HWD)      // 4096
#define LPLANE (LHD*LWD)    // 1024
#define NPIX (NB*PLANE)     // 16384

// ------- Kernel 1: channels-last transpose (raw) + raw pooled down + BN partial sums -------
__global__ void transpose_stats_kernel(const float* __restrict__ high,
                                       float* __restrict__ Ht,
                                       float* __restrict__ Dt,
                                       float* __restrict__ pS,
                                       float* __restrict__ pS2) {
    int bid = blockIdx.x;            // 4*32*4 = 512
    int cchunk = bid & 3;
    int r = (bid >> 2) & 31;
    int b = bid >> 7;
    int c0 = cchunk * 64;
    __shared__ float tile[2][64][65];
    __shared__ float sms[64][4], sms2[64][4];
    int tid = threadIdx.x;           // 256

    int xg = tid & 15;
    int jr = tid >> 4;
    #pragma unroll
    for (int i = 0; i < 8; ++i) {
        int j = i * 16 + jr;         // 0..127
        int cl = j >> 1, row = j & 1;
        const float* p = high + (((size_t)(b * CH + c0 + cl) * HH + (2 * r + row)) * HWD) + xg * 4;
        float4 v = *(const float4*)p;
        tile[row][cl][xg * 4 + 0] = v.x;
        tile[row][cl][xg * 4 + 1] = v.y;
        tile[row][cl][xg * 4 + 2] = v.z;
        tile[row][cl][xg * 4 + 3] = v.w;
    }
    __syncthreads();

    int c = tid & 63;
    int pg = tid >> 6;               // 0..3

    float s = 0.f, s2 = 0.f;
    #pragma unroll
    for (int i = 0; i < 32; ++i) {
        int pix = i * 4 + pg;        // 0..127
        int row = pix >> 6, x = pix & 63;
        float v = tile[row][c][x];
        Ht[(((size_t)(b * HH + 2 * r + row) * HWD) + x) * CH + c0 + c] = v;
        s += v; s2 += v * v;
    }
    sms[c][pg] = s; sms2[c][pg] = s2;

    #pragma unroll
    for (int i = 0; i < 8; ++i) {
        int lx = i * 4 + pg;         // 0..31
        float sum = tile[0][c][2*lx] + tile[0][c][2*lx+1]
                  + tile[1][c][2*lx] + tile[1][c][2*lx+1];
        Dt[(((size_t)(b * LHD + r) * LWD) + lx) * CH + c0 + c] = 0.25f * sum;
    }
    __syncthreads();
    if (tid < 64) {
        float S  = sms[tid][0] + sms[tid][1] + sms[tid][2] + sms[tid][3];
        float S2 = sms2[tid][0] + sms2[tid][1] + sms2[tid][2] + sms2[tid][3];
        int cg = c0 + tid;
        pS [cg * 128 + b * 32 + r] = S;
        pS2[cg * 128 + b * 32 + r] = S2;
    }
}

// ------- Kernel 2: finalize BN -> scale/shift -------
__global__ void bn_finalize_kernel(const float* __restrict__ pS,
                                   const float* __restrict__ pS2,
                                   const float* __restrict__ gamma,
                                   const float* __restrict__ beta,
                                   float* __restrict__ scale,
                                   float* __restrict__ shift) {
    int c = blockIdx.x;
    int t = threadIdx.x;             // 128
    float s  = pS [c * 128 + t];
    float s2 = pS2[c * 128 + t];
    int lane = t & 63, wid = t >> 6;
    #pragma unroll
    for (int off = 32; off > 0; off >>= 1) {
        s  += __shfl_down(s, off);
        s2 += __shfl_down(s2, off);
    }
    __shared__ float a1[2], a2[2];
    if (lane == 0) { a1[wid] = s; a2[wid] = s2; }
    __syncthreads();
    if (t == 0) {
        float S  = a1[0] + a1[1];
        float S2 = a2[0] + a2[1];
        const float invN = 1.f / (float)(NB * PLANE);
        float mean = S * invN;
        float var  = S2 * invN - mean * mean;
        float sc = gamma[c] * rsqrtf(var + 1e-5f);
        scale[c] = sc;
        shift[c] = beta[c] - mean * sc;
    }
}

// ------- Kernel 3: per-hi-pixel HSq + E[4] cross terms; extra blocks do DSq -------
__global__ void cE_dsq_kernel(const float* __restrict__ Ht,
                              const float* __restrict__ Dt,
                              const float* __restrict__ scale,
                              const float* __restrict__ shift,
                              float* __restrict__ HSq,
                              float* __restrict__ DSq,
                              float* __restrict__ E) {
    int tid = threadIdx.x;
    int lane = tid & 63, wid = tid >> 6;
    int bid = blockIdx.x;
    int c4 = lane * 4;
    float4 scv = *(const float4*)(scale + c4);
    float4 shv = *(const float4*)(shift + c4);

    if (bid < 4096) {
        int pix = bid * 4 + wid;         // [0, NPIX)
        int b = pix >> 12;
        int yx = pix & (PLANE - 1);
        int y = yx >> 6, x = yx & 63;

        float4 hr = *(const float4*)(Ht + (size_t)pix * CH + c4);
        float hx = fmaf(hr.x, scv.x, shv.x);
        float hy = fmaf(hr.y, scv.y, shv.y);
        float hz = fmaf(hr.z, scv.z, shv.z);
        float hw = fmaf(hr.w, scv.w, shv.w);

        float acc[5];
        acc[0] = hx*hx + hy*hy + hz*hz + hw*hw;

        int ey0 = (y >> 1) - 1 + (y & 1);
        int ex0 = (x >> 1) - 1 + (x & 1);
        const float* Db = Dt + (((size_t)b) << 10) * CH;
        #pragma unroll
        for (int i = 0; i < 2; ++i) {
            int ey = ey0 + i;
            #pragma unroll
            for (int j = 0; j < 2; ++j) {
                int ex = ex0 + j;
                float dot = 0.f;
                if (ey >= 0 && ey < LHD && ex >= 0 && ex < LWD) {
                    float4 dr = *(const float4*)(Db + ((size_t)((ey << 5) + ex)) * CH + c4);
                    dot  = hx * fmaf(dr.x, scv.x, shv.x);
                    dot += hy * fmaf(dr.y, scv.y, shv.y);
                    dot += hz * fmaf(dr.z, scv.z, shv.z);
                    dot += hw * fmaf(dr.w, scv.w, shv.w);
                }
                acc[1 + i * 2 + j] = dot;
            }
        }
        #pragma unroll
        for (int off = 32; off > 0; off >>= 1) {
            #pragma unroll
            for (int k = 0; k < 5; ++k) acc[k] += __shfl_xor(acc[k], off);
        }
        if (lane == 0) {
            HSq[pix] = acc[0];
            float4 ev = make_float4(-2.f*acc[1], -2.f*acc[2], -2.f*acc[3], -2.f*acc[4]);
            *(float4*)(E + (size_t)pix * 4) = ev;
        }
    } else {
        int lp = (bid - 4096) * 4 + wid;  // [0, 4096)
        float4 dr = *(const float4*)(Dt + (size_t)lp * CH + c4);
        float dx = fmaf(dr.x, scv.x, shv.x);
        float dy = fmaf(dr.y, scv.y, shv.y);
        float dz = fmaf(dr.z, scv.z, shv.z);
        float dw = fmaf(dr.w, scv.w, shv.w);
        float acc = dx*dx + dy*dy + dz*dz + dw*dw;
        #pragma unroll
        for (int off = 32; off > 0; off >>= 1) acc += __shfl_xor(acc, off);
        if (lane == 0) DSq[lp] = acc;
    }
}

// ------- Kernel 4: fused score-assembly + softmax (LDS) + weighted aggregation -------
__global__ void fused_out_kernel(const float* __restrict__ low,
                                 const float* __restrict__ HSq,
                                 const float* __restrict__ DSq,
                                 const float* __restrict__ E,
                                 const float* __restrict__ bias,
                                 float* __restrict__ out) {
    int bid = blockIdx.x;        // 1024: ((b*64)+y)*4 + lq
    int lq = bid & 3;
    int y  = (bid >> 2) & 63;
    int b  = bid >> 8;
    int tid = threadIdx.x;       // 256
    int ly = y >> 1;

    __shared__ float sc_lds[9][64];
    __shared__ float att_lds[9][64];

    // phase 1: assemble 9x64 scores for this row
    for (int it = tid; it < 576; it += 256) {
        int x = it & 63;
        int k = it >> 6;         // 0..8
        int dy = k / 3 - 1, dx = k % 3 - 1;
        int py = y + dy, px = x + dx;
        int qy = ly + dy, qx = (x >> 1) + dx;
        float s = 0.f;
        if (py >= 0 && py < HH && px >= 0 && px < HWD) {
            int pidx = (b << 12) | (py << 6) | px;
            int sy = (dy + 1 - (py & 1)) > 0;
            int sx = (dx + 1 - (px & 1)) > 0;
            s = HSq[pidx] + E[(size_t)pidx * 4 + sy * 2 + sx];
        }
        if (qy >= 0 && qy < LHD && qx >= 0 && qx < LWD)
            s += DSq[(b << 10) | (qy << 5) | qx];
        sc_lds[k][x] = s + bias[k];
    }
    __syncthreads();

    // phase 1b: softmax per x
    if (tid < 64) {
        int x = tid;
        float e[9];
        float m = -1e30f;
        #pragma unroll
        for (int k = 0; k < 9; ++k) { e[k] = sc_lds[k][x]; m = fmaxf(m, e[k]); }
        float sum = 0.f;
        #pragma unroll
        for (int k = 0; k < 9; ++k) { e[k] = __expf(e[k] - m); sum += e[k]; }
        float inv = 1.f / sum;
        #pragma unroll
        for (int k = 0; k < 9; ++k) att_lds[k][x] = e[k] * inv;
    }
    __syncthreads();

    // phase 2: aggregation
    int xg = tid & 7;
    int lg = tid >> 3;           // 0..31
    int lx0 = xg * 4;
    int x0  = xg * 8;
    int l0  = lq * 128 + lg * 4;

    float a[9][8];
    #pragma unroll
    for (int k = 0; k < 9; ++k) {
        #pragma unroll
        for (int xi = 0; xi < 8; ++xi) a[k][xi] = att_lds[k][x0 + xi];
    }

    #pragma unroll
    for (int li = 0; li < 4; ++li) {
        const float* lp = low + (size_t)(b * CL + l0 + li) * LPLANE;
        float lv[3][6];          // low x window [lx0-1, lx0+4]
        #pragma unroll
        for (int dy = 0; dy < 3; ++dy) {
            int lyy = ly + dy - 1;
            if (lyy >= 0 && lyy < LHD) {
                const float* rp = lp + lyy * LWD;
                float4 mid = *(const float4*)(rp + lx0);
                lv[dy][1] = mid.x; lv[dy][2] = mid.y; lv[dy][3] = mid.z; lv[dy][4] = mid.w;
                lv[dy][0] = (lx0 > 0) ? rp[lx0 - 1] : 0.f;
                lv[dy][5] = (lx0 + 4 < LWD) ? rp[lx0 + 4] : 0.f;
            } else {
                #pragma unroll
                for (int j = 0; j < 6; ++j) lv[dy][j] = 0.f;
            }
        }
        float o[8];
        #pragma unroll
        for (int xi = 0; xi < 8; ++xi) {
            int base = xi >> 1;
            float s = 0.f;
            #pragma unroll
            for (int k = 0; k < 9; ++k) {
                int dy = k / 3, dx = k % 3;
                s += a[k][xi] * lv[dy][base + dx];
            }
            o[xi] = s;
        }
        float* op = out + (size_t)(b * CL + l0 + li) * PLANE + (y << 6) + x0;
        *(float4*)(op)     = make_float4(o[0], o[1], o[2], o[3]);
        *(float4*)(op + 4) = make_float4(o[4], o[5], o[6], o[7]);
    }
}

extern "C" void kernel_launch(void* const* d_in, const int* in_sizes, int n_in,
                              void* d_out, int out_size, void* d_ws, size_t ws_size,
                              hipStream_t stream) {
    const float* low   = (const float*)d_in[0];
    const float* high  = (const float*)d_in[1];
    const float* gamma = (const float*)d_in[2];
    const float* beta  = (const float*)d_in[3];
    const float* bias  = (const float*)d_in[4];
    float* out = (float*)d_out;

    float* ws = (float*)d_ws;
    float* pS    = ws;                        // 32768
    float* pS2   = pS + 32768;                // 32768
    float* scale = pS2 + 32768;               // 256
    float* shift = scale + 256;               // 256
    float* Ht    = shift + 256;               // 4194304
    float* Dt    = Ht + (size_t)NB * PLANE * CH;    // 1048576
    float* HSq   = Dt + (size_t)NB * LPLANE * CH;   // 16384
    float* DSq   = HSq + NPIX;                // 4096
    float* E     = DSq + NB * LPLANE;         // 65536

    transpose_stats_kernel<<<512, 256, 0, stream>>>(high, Ht, Dt, pS, pS2);
    bn_finalize_kernel<<<256, 128, 0, stream>>>(pS, pS2, gamma, beta, scale, shift);
    cE_dsq_kernel<<<5120, 256, 0, stream>>>(Ht, Dt, scale, shift, HSq, DSq, E);
    fused_out_kernel<<<1024, 256, 0, stream>>>(low, HSq, DSq, E, bias, out);
}

// Round 6
// 33.702 us; speedup vs baseline: 4.3692x; 1.1810x over previous
//
#include <hip/hip_runtime.h>

#define NB 4
#define CH 256
#define CL 512
#define HH 64
#define HWD 64
#define LHD 32
#define LWD 32
#define PLANE (HH*HWD)      // 4096
#define LPLANE (LHD*LWD)    // 1024
#define NPIX (NB*PLANE)     // 16384
#define DPH 34              // padded pooled dims (1-halo)
#define DPLANE (DPH*DPH)    // 1156

// ------- Kernel 1: BN partial sums + raw 2x2 pool into halo-padded Dlowp -------
// Block = (b, c): 1024 blocks x 256 threads.
__global__ void stats_pool_kernel(const float* __restrict__ high,
                                  float* __restrict__ Dlowp,
                                  float* __restrict__ pS,
                                  float* __restrict__ pS2) {
    int bid = blockIdx.x;
    int c = bid & 255, b = bid >> 8;
    int tid = threadIdx.x;
    const float* hp = high + (((size_t)(b * CH + c)) << 12);
    float* dp = Dlowp + ((size_t)(b * CH + c)) * DPLANE;

    int xg = tid & 15;           // 16 x-groups of 4
    int rp0 = tid >> 4;          // row-pair base 0..15
    float s = 0.f, s2 = 0.f;
    #pragma unroll
    for (int i = 0; i < 2; ++i) {
        int rp = rp0 + 16 * i;   // 0..31
        const float* r0 = hp + (rp * 2) * HWD + xg * 4;
        float4 v0 = *(const float4*)r0;
        float4 v1 = *(const float4*)(r0 + HWD);
        s  += v0.x + v0.y + v0.z + v0.w + v1.x + v1.y + v1.z + v1.w;
        s2 += v0.x*v0.x + v0.y*v0.y + v0.z*v0.z + v0.w*v0.w
            + v1.x*v1.x + v1.y*v1.y + v1.z*v1.z + v1.w*v1.w;
        float p0 = 0.25f * (v0.x + v0.y + v1.x + v1.y);
        float p1 = 0.25f * (v0.z + v0.w + v1.z + v1.w);
        dp[(rp + 1) * DPH + 2 * xg + 1] = p0;
        dp[(rp + 1) * DPH + 2 * xg + 2] = p1;
    }
    // zero halo
    if (tid < DPH) { dp[tid] = 0.f; dp[33 * DPH + tid] = 0.f; }
    if (tid < 32)  { dp[(tid + 1) * DPH] = 0.f; dp[(tid + 1) * DPH + 33] = 0.f; }

    // block reduce
    __shared__ float sm1[4], sm2[4];
    int lane = tid & 63, wid = tid >> 6;
    #pragma unroll
    for (int off = 32; off > 0; off >>= 1) {
        s  += __shfl_down(s, off);
        s2 += __shfl_down(s2, off);
    }
    if (lane == 0) { sm1[wid] = s; sm2[wid] = s2; }
    __syncthreads();
    if (tid == 0) {
        pS [c * 4 + b] = sm1[0] + sm1[1] + sm1[2] + sm1[3];
        pS2[c * 4 + b] = sm2[0] + sm2[1] + sm2[2] + sm2[3];
    }
}

// ------- Kernel 2: channel-major HSq + E[4] + DSq -------
// Block = (b, y): 256 blocks x 512 threads. chunk = tid>>4 (32 chunks x 8 c), xi = tid&15 (4 x each).
__global__ __launch_bounds__(512) void cE_kernel(const float* __restrict__ high,
                                                 const float* __restrict__ Dlowp,
                                                 const float* __restrict__ pS,
                                                 const float* __restrict__ pS2,
                                                 const float* __restrict__ gamma,
                                                 const float* __restrict__ beta,
                                                 float* __restrict__ HSq,
                                                 float* __restrict__ DSq,
                                                 float* __restrict__ E) {
    int bid = blockIdx.x;
    int y = bid & 63, b = bid >> 6;
    int tid = threadIdx.x;

    __shared__ float sc_s[256], sh_s[256];
    __shared__ float red[32][64][5];     // 40 KB
    __shared__ float red2[32][32];       // 4 KB

    if (tid < 256) {
        int c = tid;
        float4 s4 = *(const float4*)(pS + c * 4);
        float4 q4 = *(const float4*)(pS2 + c * 4);
        float S  = s4.x + s4.y + s4.z + s4.w;
        float S2 = q4.x + q4.y + q4.z + q4.w;
        const float invN = 1.f / (float)(NB * PLANE);
        float mean = S * invN;
        float var  = S2 * invN - mean * mean;
        float sc = gamma[c] * rsqrtf(var + 1e-5f);
        sc_s[c] = sc;
        sh_s[c] = beta[c] - mean * sc;
    }
    __syncthreads();

    int xi = tid & 15, chunk = tid >> 4;
    int x0 = xi * 4;
    int k = 2 * xi;
    int ey0 = (y >> 1) - 1 + (y & 1);
    bool row0_oob = (ey0 < 0);           // only y == 0
    bool row1_oob = (ey0 + 1 > 31);      // only y == 63
    bool col0_oob = (xi == 0);
    bool col3_oob = (xi == 15);

    float a[4][5];
    #pragma unroll
    for (int m = 0; m < 4; ++m)
        #pragma unroll
        for (int s = 0; s < 5; ++s) a[m][s] = 0.f;
    float dsq0 = 0.f, dsq1 = 0.f;

    #pragma unroll
    for (int j = 0; j < 8; ++j) {
        int c = chunk * 8 + j;
        float sc = sc_s[c], sh = sh_s[c];
        float4 hr = *(const float4*)(high + ((((size_t)(b * CH + c)) << 12) | (y << 6) | x0));
        float h0 = fmaf(hr.x, sc, sh);
        float h1 = fmaf(hr.y, sc, sh);
        float h2 = fmaf(hr.z, sc, sh);
        float h3 = fmaf(hr.w, sc, sh);

        const float* dp = Dlowp + ((size_t)(b * CH + c)) * DPLANE + (ey0 + 1) * DPH + k;
        float2 d0a = *(const float2*)(dp);
        float2 d0b = *(const float2*)(dp + 2);
        float2 d1a = *(const float2*)(dp + DPH);
        float2 d1b = *(const float2*)(dp + DPH + 2);
        float d0[4] = { fmaf(d0a.x, sc, sh), fmaf(d0a.y, sc, sh),
                        fmaf(d0b.x, sc, sh), fmaf(d0b.y, sc, sh) };
        float d1[4] = { fmaf(d1a.x, sc, sh), fmaf(d1a.y, sc, sh),
                        fmaf(d1b.x, sc, sh), fmaf(d1b.y, sc, sh) };
        if (row0_oob) { d0[0] = d0[1] = d0[2] = d0[3] = 0.f; }
        if (row1_oob) { d1[0] = d1[1] = d1[2] = d1[3] = 0.f; }
        if (col0_oob) { d0[0] = 0.f; d1[0] = 0.f; }
        if (col3_oob) { d0[3] = 0.f; d1[3] = 0.f; }

        float h[4] = { h0, h1, h2, h3 };
        #pragma unroll
        for (int m = 0; m < 4; ++m) {
            const int base = (m >> 1) + (m & 1);   // 0,1,1,2
            a[m][0] = fmaf(h[m], h[m],        a[m][0]);
            a[m][1] = fmaf(h[m], d0[base],     a[m][1]);   // sy0 sx0
            a[m][2] = fmaf(h[m], d0[base + 1], a[m][2]);   // sy0 sx1
            a[m][3] = fmaf(h[m], d1[base],     a[m][3]);   // sy1 sx0
            a[m][4] = fmaf(h[m], d1[base + 1], a[m][4]);   // sy1 sx1
        }
        // DSq row (ey = ly) is d1 when y even; cols local 1,2 = lx 2xi, 2xi+1
        dsq0 = fmaf(d1[1], d1[1], dsq0);
        dsq1 = fmaf(d1[2], d1[2], dsq1);
    }

    #pragma unroll
    for (int m = 0; m < 4; ++m)
        #pragma unroll
        for (int s = 0; s < 5; ++s) red[chunk][x0 + m][s] = a[m][s];
    red2[chunk][2 * xi]     = dsq0;
    red2[chunk][2 * xi + 1] = dsq1;
    __syncthreads();

    int px = tid & 63, r = tid >> 6;     // r = 0..7
    if (r < 5) {
        float s = 0.f;
        #pragma unroll
        for (int ch = 0; ch < 32; ++ch) s += red[ch][px][r];
        int pix = (b << 12) | (y << 6) | px;
        if (r == 0) HSq[pix] = s;
        else        E[(size_t)pix * 4 + (r - 1)] = -2.f * s;
    } else if (r == 5 && (y & 1) == 0 && px < 32) {
        float s = 0.f;
        #pragma unroll
        for (int ch = 0; ch < 32; ++ch) s += red2[ch][px];
        DSq[(b << 10) | ((y >> 1) << 5) | px] = s;
    }
}

// ------- Kernel 3: fused score-assembly + softmax (LDS) + weighted aggregation -------
__global__ void fused_out_kernel(const float* __restrict__ low,
                                 const float* __restrict__ HSq,
                                 const float* __restrict__ DSq,
                                 const float* __restrict__ E,
                                 const float* __restrict__ bias,
                                 float* __restrict__ out) {
    int bid = blockIdx.x;        // 1024: ((b*64)+y)*4 + lq
    int lq = bid & 3;
    int y  = (bid >> 2) & 63;
    int b  = bid >> 8;
    int tid = threadIdx.x;       // 256
    int ly = y >> 1;

    __shared__ float sc_lds[9][64];
    __shared__ float att_lds[9][64];

    for (int it = tid; it < 576; it += 256) {
        int x = it & 63;
        int k = it >> 6;         // 0..8
        int dy = k / 3 - 1, dx = k % 3 - 1;
        int py = y + dy, px = x + dx;
        int qy = ly + dy, qx = (x >> 1) + dx;
        float s = 0.f;
        if (py >= 0 && py < HH && px >= 0 && px < HWD) {
            int pidx = (b << 12) | (py << 6) | px;
            int sy = (dy + 1 - (py & 1)) > 0;
            int sx = (dx + 1 - (px & 1)) > 0;
            s = HSq[pidx] + E[(size_t)pidx * 4 + sy * 2 + sx];
        }
        if (qy >= 0 && qy < LHD && qx >= 0 && qx < LWD)
            s += DSq[(b << 10) | (qy << 5) | qx];
        sc_lds[k][x] = s + bias[k];
    }
    __syncthreads();

    if (tid < 64) {
        int x = tid;
        float e[9];
        float m = -1e30f;
        #pragma unroll
        for (int k = 0; k < 9; ++k) { e[k] = sc_lds[k][x]; m = fmaxf(m, e[k]); }
        float sum = 0.f;
        #pragma unroll
        for (int k = 0; k < 9; ++k) { e[k] = __expf(e[k] - m); sum += e[k]; }
        float inv = 1.f / sum;
        #pragma unroll
        for (int k = 0; k < 9; ++k) att_lds[k][x] = e[k] * inv;
    }
    __syncthreads();

    int xg = tid & 7;
    int lg = tid >> 3;           // 0..31
    int lx0 = xg * 4;
    int x0  = xg * 8;
    int l0  = lq * 128 + lg * 4;

    float a[9][8];
    #pragma unroll
    for (int k = 0; k < 9; ++k) {
        #pragma unroll
        for (int xi = 0; xi < 8; ++xi) a[k][xi] = att_lds[k][x0 + xi];
    }

    #pragma unroll
    for (int li = 0; li < 4; ++li) {
        const float* lp = low + (size_t)(b * CL + l0 + li) * LPLANE;
        float lv[3][6];
        #pragma unroll
        for (int dy = 0; dy < 3; ++dy) {
            int lyy = ly + dy - 1;
            if (lyy >= 0 && lyy < LHD) {
                const float* rp = lp + lyy * LWD;
                float4 mid = *(const float4*)(rp + lx0);
                lv[dy][1] = mid.x; lv[dy][2] = mid.y; lv[dy][3] = mid.z; lv[dy][4] = mid.w;
                lv[dy][0] = (lx0 > 0) ? rp[lx0 - 1] : 0.f;
                lv[dy][5] = (lx0 + 4 < LWD) ? rp[lx0 + 4] : 0.f;
            } else {
                #pragma unroll
                for (int j = 0; j < 6; ++j) lv[dy][j] = 0.f;
            }
        }
        float o[8];
        #pragma unroll
        for (int xi = 0; xi < 8; ++xi) {
            int base = xi >> 1;
            float s = 0.f;
            #pragma unroll
            for (int k = 0; k < 9; ++k) {
                int dy = k / 3, dx = k % 3;
                s += a[k][xi] * lv[dy][base + dx];
            }
            o[xi] = s;
        }
        float* op = out + (size_t)(b * CL + l0 + li) * PLANE + (y << 6) + x0;
        *(float4*)(op)     = make_float4(o[0], o[1], o[2], o[3]);
        *(float4*)(op + 4) = make_float4(o[4], o[5], o[6], o[7]);
    }
}

extern "C" void kernel_launch(void* const* d_in, const int* in_sizes, int n_in,
                              void* d_out, int out_size, void* d_ws, size_t ws_size,
                              hipStream_t stream) {
    const float* low   = (const float*)d_in[0];
    const float* high  = (const float*)d_in[1];
    const float* gamma = (const float*)d_in[2];
    const float* beta  = (const float*)d_in[3];
    const float* bias  = (const float*)d_in[4];
    float* out = (float*)d_out;

    float* ws = (float*)d_ws;
    float* pS    = ws;                                // 1024
    float* pS2   = pS + 1024;                         // 1024
    float* Dlowp = pS2 + 1024;                        // 4*256*1156 = 1183744
    float* HSq   = Dlowp + (size_t)NB * CH * DPLANE;  // 16384
    float* DSq   = HSq + NPIX;                        // 4096
    float* E     = DSq + NB * LPLANE;                 // 65536

    stats_pool_kernel<<<1024, 256, 0, stream>>>(high, Dlowp, pS, pS2);
    cE_kernel<<<256, 512, 0, stream>>>(high, Dlowp, pS, pS2, gamma, beta, HSq, DSq, E);
    fused_out_kernel<<<1024, 256, 0, stream>>>(low, HSq, DSq, E, bias, out);
}